// Round 16
// baseline (264.270 us; speedup 1.0000x reference)
//
#include <hip/hip_runtime.h>
#include <hip/hip_bf16.h>

using bf16 = __hip_bfloat16;
typedef __attribute__((ext_vector_type(8))) short short8;
typedef __attribute__((ext_vector_type(4))) float floatx4;

#define NB 4
#define NSEQ 4096
#define DIM 1024
#define INNER 512
#define TOK (NB * NSEQ)   // 16384

// -------------------------- memory plan (no d_ws) ---------------------------
// x buf (64 MiB fp32): PRISTINE (read by prep + k4).
// d_out (64 MiB):
//   [0,32)   xb bf16 [16384][1024]    (prep writes; k1 reads; dead before k4)
//   [32,48)  ctx_part fp32 [128][8][64][64] (k1 writes; k2 reads)
//   [48,50)  wkvb bf16 [1024][1024]   (prep writes; k1 reads)
//   [50,54)  M2 bf16 [4096][512]      (k2 writes; k3 reads)
//   [54,54.5) wqT bf16 [1024][512]    (prep writes; k3 reads)
//   [0,64)   final output             (k4 — reads NOTHING in d_out)
// w_qkv buf (6 MiB fp32): prep reads; then k3 overwrites with W2 batches 0-2.
// w_out buf (2 MiB fp32): k2 reads; then k3 overwrites with W2 batch 3.
// R14 verdict: fp32-A reg-staging in k1 = latency hole (72us, 840 GB/s, both
// pipes <20%). R10 proved the all-async shape sustains 2.59 TB/s. So: pay the
// 32MB x-convert once in prep, run k1 all-async bf16 + XCD swizzle.

__device__ inline unsigned short f2bf(float x) {
  union { bf16 h; unsigned short u; } c; c.h = __float2bfloat16(x); return c.u;
}
__device__ inline float bf2f(unsigned short u) {
  return __uint_as_float((unsigned)u << 16);
}
__device__ inline uint4 pack8(const float4 a, const float4 b) {
  union { uint4 u; unsigned short h[8]; } p;
  p.h[0] = f2bf(a.x); p.h[1] = f2bf(a.y); p.h[2] = f2bf(a.z); p.h[3] = f2bf(a.w);
  p.h[4] = f2bf(b.x); p.h[5] = f2bf(b.y); p.h[6] = f2bf(b.z); p.h[7] = f2bf(b.w);
  return p.u;
}

// async global->LDS, 16 B per lane; HW writes lane i at ldsbase + i*16.
__device__ inline void gload_lds16(const bf16* g, bf16* ldsbase) {
  __builtin_amdgcn_global_load_lds(
      (const __attribute__((address_space(1))) void*)g,
      (__attribute__((address_space(3))) void*)ldsbase, 16, 0, 0);
}

// ---------------------------------------------------------------------------
// prep: blocks [0,8192)      x fp32 -> xb bf16
//       blocks [8192,8704)   w_kv fp32 -> wkvb bf16
//       blocks [8704,8832)   wq -> wqT bf16 (transpose)
// (R7/R8-verified kernel, verbatim.)
// ---------------------------------------------------------------------------
__global__ __launch_bounds__(256)
void fused_prep(const float* __restrict__ x, const float* __restrict__ w_qkv,
                bf16* __restrict__ xb, bf16* __restrict__ wkvb,
                bf16* __restrict__ wqT) {
  const int tid = threadIdx.x;
  const int blk = blockIdx.x;

  if (blk < 8192) {
    const size_t i = (size_t)blk * 256 + tid;
    const float* src = x + i * 8;
    *(uint4*)(xb + i * 8) = pack8(((const float4*)src)[0], ((const float4*)src)[1]);
  } else if (blk < 8704) {
    const size_t i = (size_t)(blk - 8192) * 256 + tid;
    const float* src = w_qkv + (size_t)INNER * DIM + i * 8;
    *(uint4*)(wkvb + i * 8) = pack8(((const float4*)src)[0], ((const float4*)src)[1]);
  } else {
    __shared__ unsigned short t[64 * 68];
    const int q  = blk - 8704;
    const int c0 = (q & 15) * 64;
    const int r0 = (q >> 4) * 64;
#pragma unroll
    for (int l = 0; l < 4; ++l) {
      const int s = l * 256 + tid;
      const int row = s >> 4, col4 = s & 15;
      const float4 v = *(const float4*)(w_qkv + (size_t)(r0 + row) * 1024 + c0 + col4 * 4);
      t[row * 68 + col4 * 4 + 0] = f2bf(v.x);
      t[row * 68 + col4 * 4 + 1] = f2bf(v.y);
      t[row * 68 + col4 * 4 + 2] = f2bf(v.z);
      t[row * 68 + col4 * 4 + 3] = f2bf(v.w);
    }
    __syncthreads();
#pragma unroll
    for (int l = 0; l < 2; ++l) {
      const int s = l * 256 + tid;
      const int cc = s >> 3, g = s & 7;
      union { uint4 u; unsigned short h[8]; } o;
#pragma unroll
      for (int u = 0; u < 8; ++u) o.h[u] = t[(g * 8 + u) * 68 + cc];
      *(uint4*)((unsigned short*)wqT + (size_t)(c0 + cc) * 512 + r0 + g * 8) = o.u;
    }
  }
}

// ---------------------------------------------------------------------------
// k1: fused kv-GEMM + softmax(k) + ctx partial — R10's all-bf16 async kernel
// (verified: 58us BW-bound at 2.59 TB/s over 152MB) + R11's proven XCD
// swizzle (FETCH 132->~42MB). Both operands via gload_lds; no synchronous
// load round-trip in the K-loop (R14 showed fp32-A reg-staging = 72us
// latency hole). Grid 1024: h=(p>>3)&7, m_tile=(p&7)+(p>>6)*8 (bijective) —
// all 8 head-blocks of an m-tile on one XCD, A-panel L2-shared.
// Epilogue: verified softmax+ctx (absmax 0.75 across R10/R11/R14).
// ---------------------------------------------------------------------------
__global__ __launch_bounds__(256, 4)
void kv_softmax_ctx(const bf16* __restrict__ A, const bf16* __restrict__ Wkv,
                    float* __restrict__ ctx_part) {
  __shared__ __align__(16) char smem[33280];
  bf16* As = (bf16*)smem;                                   // [128][64]
  bf16* Bs = (bf16*)(smem + 16384);                         // [128][64]
  unsigned short* skT = (unsigned short*)smem;              // [64][130]
  unsigned short* vT  = (unsigned short*)(smem + 16640);    // [64][130]

  const int tid    = threadIdx.x;
  const int p      = blockIdx.x;
  const int h      = (p >> 3) & 7;
  const int m_tile = (p & 7) + (p >> 6) * 8;   // 0..127, XCD-contiguous
  const int m0     = m_tile * 128;

  const int wave = tid >> 6;
  const int lane = tid & 63;
  const int wr   = (wave >> 1) * 64;
  const int wc   = (wave & 1) * 64;
  const int quad = lane >> 4;
  const int r16  = lane & 15;
  const int rxor = r16 & 7;
  const int lrow = lane >> 3;
  const int lcol = lane & 7;
  const int gchunk = lcol ^ lrow;

  floatx4 acc[4][4];
#pragma unroll
  for (int i = 0; i < 4; ++i)
#pragma unroll
    for (int j = 0; j < 4; ++j) acc[i][j] = (floatx4)0.0f;

  for (int kt = 0; kt < 16; ++kt) {
    const int k0 = kt << 6;
#pragma unroll
    for (int t = 0; t < 4; ++t) {
      const int s   = wave * 4 + t;
      const int row = s * 8 + lrow;
      // B rows: 0-63 -> wkvb row h*64+row (k-head); 64-127 -> 448+h*64+row (v)
      const int badd = (s * 8 >= 64) ? (448 + h * 64) : (h * 64);
      gload_lds16(A   + (size_t)(m0 + row) * 1024 + k0 + gchunk * 8, As + s * 512);
      gload_lds16(Wkv + (size_t)(badd + row) * 1024 + k0 + gchunk * 8, Bs + s * 512);
    }
    __syncthreads();
#pragma unroll
    for (int kk = 0; kk < 64; kk += 32) {
      const int cbase = kk >> 3;
      short8 af[4], bfg[4];
#pragma unroll
      for (int i = 0; i < 4; ++i)
        af[i] = *(const short8*)(As + (wr + i * 16 + r16) * 64 + (((quad + cbase) ^ rxor) << 3));
#pragma unroll
      for (int j = 0; j < 4; ++j)
        bfg[j] = *(const short8*)(Bs + (wc + j * 16 + r16) * 64 + (((quad + cbase) ^ rxor) << 3));
#pragma unroll
      for (int i = 0; i < 4; ++i)
#pragma unroll
        for (int j = 0; j < 4; ++j)
          acc[i][j] = __builtin_amdgcn_mfma_f32_16x16x32_bf16(af[i], bfg[j], acc[i][j], 0, 0, 0);
    }
    __syncthreads();   // all As/Bs reads done -> safe to overlay skT/vT
  }

  // ---- epilogue: softmax (k-waves) / passthrough (v-waves), transposed store
  const int rowbase = wr + quad * 4;
  if ((wave & 1) == 0) {
#pragma unroll
    for (int i = 0; i < 4; ++i)
#pragma unroll
      for (int reg = 0; reg < 4; ++reg) {
        float kf[4];
#pragma unroll
        for (int j = 0; j < 4; ++j) kf[j] = bf2f(f2bf(acc[i][j][reg]));
        float mx = fmaxf(fmaxf(kf[0], kf[1]), fmaxf(kf[2], kf[3]));
        mx = fmaxf(mx, __shfl_xor(mx, 1, 64));
        mx = fmaxf(mx, __shfl_xor(mx, 2, 64));
        mx = fmaxf(mx, __shfl_xor(mx, 4, 64));
        mx = fmaxf(mx, __shfl_xor(mx, 8, 64));
        float e[4]; float s = 0.0f;
#pragma unroll
        for (int j = 0; j < 4; ++j) { e[j] = __expf(kf[j] - mx); s += e[j]; }
        s += __shfl_xor(s, 1, 64);
        s += __shfl_xor(s, 2, 64);
        s += __shfl_xor(s, 4, 64);
        s += __shfl_xor(s, 8, 64);
        const float inv = 1.0f / s;
        const int row = rowbase + i * 16 + reg;
#pragma unroll
        for (int j = 0; j < 4; ++j)
          skT[(j * 16 + r16) * 130 + row] = f2bf(e[j] * inv);
      }
  } else {
#pragma unroll
    for (int i = 0; i < 4; ++i)
#pragma unroll
      for (int reg = 0; reg < 4; ++reg) {
        const int row = rowbase + i * 16 + reg;
#pragma unroll
        for (int j = 0; j < 4; ++j)
          vT[(j * 16 + r16) * 130 + row] = f2bf(acc[i][j][reg]);
      }
  }
  __syncthreads();

  // ---- ctx MFMA: ctx[d][e] = sum over 128 rows of sk[row][d]*v[row][e]
  const int d0 = wave * 16;
  floatx4 cacc[4];
#pragma unroll
  for (int j = 0; j < 4; ++j) cacc[j] = (floatx4)0.0f;
#pragma unroll
  for (int kk = 0; kk < 4; ++kk) {
    const int kof = kk * 32 + quad * 8;
    union { short8 v; unsigned u[4]; } afr;
    {
      const unsigned* qa = (const unsigned*)(skT + (d0 + r16) * 130 + kof);
      afr.u[0] = qa[0]; afr.u[1] = qa[1]; afr.u[2] = qa[2]; afr.u[3] = qa[3];
    }
#pragma unroll
    for (int j = 0; j < 4; ++j) {
      union { short8 v; unsigned u[4]; } bfr;
      const unsigned* qb = (const unsigned*)(vT + (j * 16 + r16) * 130 + kof);
      bfr.u[0] = qb[0]; bfr.u[1] = qb[1]; bfr.u[2] = qb[2]; bfr.u[3] = qb[3];
      cacc[j] = __builtin_amdgcn_mfma_f32_16x16x32_bf16(afr.v, bfr.v, cacc[j], 0, 0, 0);
    }
  }

  float* cg = ctx_part + (size_t)(m_tile * 8 + h) * 4096;
#pragma unroll
  for (int j = 0; j < 4; ++j) {
    const int e = j * 16 + r16;
#pragma unroll
    for (int r = 0; r < 4; ++r) {
      const int d = d0 + quad * 4 + r;
      cg[d * 64 + e] = cacc[j][r];
    }
  }
}

// ---------------------------------------------------------------------------
// k2: M2[b*1024+o][h*64+d] = sum_e w_out[o][h*64+e] * ctx[b,h][d][e].
// ctx[b,h] = sum of the batch's 32 m-tile partials (R10-verified).
// ---------------------------------------------------------------------------
__global__ __launch_bounds__(256)
void build_m2(const float* __restrict__ w_out, const float* __restrict__ ctx_part,
              bf16* __restrict__ M2) {
  __shared__ unsigned short wo_s[128 * 68];
  __shared__ __align__(16) float ctx_s[4096];

  const int tid = threadIdx.x;
  const int bh  = blockIdx.y;
  const int b   = bh >> 3, h = bh & 7;
  const int o0  = blockIdx.x * 128;

#pragma unroll
  for (int l = 0; l < 8; ++l) {
    const int s = l * 256 + tid;
    const int row = s >> 4, col4 = s & 15;
    const float4 v = *(const float4*)(w_out + (size_t)(o0 + row) * 512 + h * 64 + col4 * 4);
    wo_s[row * 68 + col4 * 4 + 0] = f2bf(v.x);
    wo_s[row * 68 + col4 * 4 + 1] = f2bf(v.y);
    wo_s[row * 68 + col4 * 4 + 2] = f2bf(v.z);
    wo_s[row * 68 + col4 * 4 + 3] = f2bf(v.w);
  }
  const float4* cg = (const float4*)(ctx_part + (size_t)(b * 256 + h) * 4096);
#pragma unroll
  for (int l = 0; l < 4; ++l) {
    const int idx = l * 256 + tid;
    float4 s = make_float4(0.f, 0.f, 0.f, 0.f);
#pragma unroll
    for (int sl = 0; sl < 32; ++sl) {
      const float4 v = cg[(size_t)sl * 8192 + idx];
      s.x += v.x; s.y += v.y; s.z += v.z; s.w += v.w;
    }
    ((float4*)ctx_s)[idx] = s;
  }
  __syncthreads();

  const int o_loc = tid & 127;
  const int dbase = (tid >> 7) * 32;
  float acc[32];
#pragma unroll
  for (int d = 0; d < 32; ++d) acc[d] = 0.0f;

  for (int e = 0; e < 64; ++e) {
    const float wf = bf2f(wo_s[o_loc * 68 + e]);
#pragma unroll
    for (int d = 0; d < 32; ++d)
      acc[d] += wf * ctx_s[(dbase + d) * 64 + e];
  }

  union { uint4 u[4]; unsigned short hh[32]; } o;
#pragma unroll
  for (int d = 0; d < 32; ++d) o.hh[d] = f2bf(acc[d]);
  unsigned short* dst = (unsigned short*)M2 + (size_t)(b * 1024 + o0 + o_loc) * 512 + h * 64 + dbase;
#pragma unroll
  for (int i = 0; i < 4; ++i) ((uint4*)dst)[i] = o.u[i];
}

// ---------------------------------------------------------------------------
// k3: 128x128 bf16 GEMM (W2 = M2 @ wqT^T). Rows >= msplit go to Calt.
// ---------------------------------------------------------------------------
template <typename TO>
__global__ __launch_bounds__(256, 4)
void gemm_bt(const bf16* __restrict__ A, int lda,
             const bf16* __restrict__ W, int mTiles,
             TO* __restrict__ C, int ldc, int K,
             TO* __restrict__ Calt, int msplit) {
  __shared__ __align__(16) bf16 As[128 * 64];
  __shared__ __align__(16) bf16 Bs[128 * 64];

  const int tid    = threadIdx.x;
  const int p      = blockIdx.x;
  const int m_tile = p % mTiles;
  const int n_tile = p / mTiles;
  const int m0     = m_tile * 128;
  const int n0     = n_tile * 128;

  const int wave = tid >> 6;
  const int lane = tid & 63;
  const int wr   = (wave >> 1) * 64;
  const int wc   = (wave & 1) * 64;
  const int quad = lane >> 4;
  const int r16  = lane & 15;
  const int rxor = r16 & 7;
  const int lrow = lane >> 3;
  const int lcol = lane & 7;
  const int gchunk = lcol ^ lrow;

  floatx4 acc[4][4];
#pragma unroll
  for (int i = 0; i < 4; ++i)
#pragma unroll
    for (int j = 0; j < 4; ++j) acc[i][j] = (floatx4)0.0f;

  const int ksteps = K >> 6;
  for (int kt = 0; kt < ksteps; ++kt) {
    const int k0 = kt << 6;
#pragma unroll
    for (int t = 0; t < 4; ++t) {
      const int s   = wave * 4 + t;
      const int row = s * 8 + lrow;
      gload_lds16(A + (size_t)(m0 + row) * lda + k0 + gchunk * 8, As + s * 512);
      gload_lds16(W + (size_t)(n0 + row) * K   + k0 + gchunk * 8, Bs + s * 512);
    }
    __syncthreads();
#pragma unroll
    for (int kk = 0; kk < 64; kk += 32) {
      const int cbase = kk >> 3;
      short8 af[4], bfg[4];
#pragma unroll
      for (int i = 0; i < 4; ++i)
        af[i] = *(const short8*)(As + (wr + i * 16 + r16) * 64 + (((quad + cbase) ^ rxor) << 3));
#pragma unroll
      for (int j = 0; j < 4; ++j)
        bfg[j] = *(const short8*)(Bs + (wc + j * 16 + r16) * 64 + (((quad + cbase) ^ rxor) << 3));
#pragma unroll
      for (int i = 0; i < 4; ++i)
#pragma unroll
        for (int j = 0; j < 4; ++j)
          acc[i][j] = __builtin_amdgcn_mfma_f32_16x16x32_bf16(af[i], bfg[j], acc[i][j], 0, 0, 0);
    }
    __syncthreads();
  }

  TO* Cb = C; int radj = 0;
  if (Calt && m0 >= msplit) { Cb = Calt; radj = msplit; }
#pragma unroll
  for (int j = 0; j < 4; ++j) {
    const int col = n0 + wc + j * 16 + r16;
#pragma unroll
    for (int i = 0; i < 4; ++i) {
      const int rowb = m0 + wr + i * 16 + quad * 4 - radj;
#pragma unroll
      for (int r = 0; r < 4; ++r)
        Cb[(size_t)(rowb + r) * ldc + col] = __float2bfloat16(acc[i][j][r]);
    }
  }
}

// ---------------------------------------------------------------------------
// k4: out = bf16(A_fp32) @ W2[batch]^T + bias (R14's kernel, verbatim —
// must read pristine fp32 x because its output overwrites xb's region).
// 128x128 tiles, grid 1024, XCD-swizzled; A fp32 reg-staged, B async.
// ---------------------------------------------------------------------------
__global__ __launch_bounds__(256, 4)
void gemm_f32a(const float* __restrict__ A,
               const bf16* __restrict__ W, size_t wbatch,
               const bf16* __restrict__ Walt,
               const float* __restrict__ bias,
               float* __restrict__ C, int ldc) {
  __shared__ __align__(16) bf16 As[128 * 64];
  __shared__ __align__(16) bf16 Bs[128 * 64];

  const int tid    = threadIdx.x;
  const int p      = blockIdx.x;
  const int n_tile = (p >> 3) & 7;
  const int m_tile = (p & 7) + (p >> 6) * 8;   // 0..127, XCD-contiguous
  const int m0 = m_tile * 128, n0 = n_tile * 128;
  const int batch = m_tile >> 5;
  const bf16* Wp = (batch == 3 && Walt) ? Walt : W + (size_t)batch * wbatch;

  const int wave = tid >> 6;
  const int lane = tid & 63;
  const int wr   = (wave >> 1) * 64;
  const int wc   = (wave & 1) * 64;
  const int quad = lane >> 4;
  const int r16  = lane & 15;
  const int rxor = r16 & 7;
  const int lrow = lane >> 3;
  const int lcol = lane & 7;
  const int gchunk = lcol ^ lrow;
  const int wb = wave * 8 + lrow;

  const float* Ax = A + (size_t)(m0 + wb) * 1024 + lcol * 8;

  floatx4 acc[4][4];
#pragma unroll
  for (int i = 0; i < 4; ++i)
#pragma unroll
    for (int j = 0; j < 4; ++j) acc[i][j] = (floatx4)0.0f;

  for (int kt = 0; kt < 16; ++kt) {
    const int k0 = kt << 6;
#pragma unroll
    for (int t = 0; t < 4; ++t) {
      const int s   = wave * 4 + t;
      const int row = s * 8 + lrow;
      gload_lds16(Wp + (size_t)(n0 + row) * 1024 + k0 + gchunk * 8, Bs + s * 512);
    }
    float4 rA[8];
#pragma unroll
    for (int l = 0; l < 4; ++l) {
      rA[2 * l]     = *(const float4*)(Ax + (size_t)l * 32768 + k0);
      rA[2 * l + 1] = *(const float4*)(Ax + (size_t)l * 32768 + k0 + 4);
    }
#pragma unroll
    for (int l = 0; l < 4; ++l) {
      const int row = l * 32 + wb;       // row&7 == lrow
      *(uint4*)(As + row * 64 + ((lcol ^ lrow) << 3)) = pack8(rA[2 * l], rA[2 * l + 1]);
    }
    __syncthreads();   // drains vm (Bs landed) + lgkm (As writes visible)
#pragma unroll
    for (int kk = 0; kk < 64; kk += 32) {
      const int cbase = kk >> 3;
      short8 af[4], bfg[4];
#pragma unroll
      for (int i = 0; i < 4; ++i)
        af[i] = *(const short8*)(As + (wr + i * 16 + r16) * 64 + (((quad + cbase) ^ rxor) << 3));
#pragma unroll
      for (int j = 0; j < 4; ++j)
        bfg[j] = *(const short8*)(Bs + (wc + j * 16 + r16) * 64 + (((quad + cbase) ^ rxor) << 3));
#pragma unroll
      for (int i = 0; i < 4; ++i)
#pragma unroll
        for (int j = 0; j < 4; ++j)
          acc[i][j] = __builtin_amdgcn_mfma_f32_16x16x32_bf16(af[i], bfg[j], acc[i][j], 0, 0, 0);
    }
    __syncthreads();
  }

  // D mapping (verified m89/m91): row = quad*4 + reg, col = lane&15
#pragma unroll
  for (int j = 0; j < 4; ++j) {
    const int col = n0 + wc + j * 16 + r16;
    const float bv = bias[col];
#pragma unroll
    for (int i = 0; i < 4; ++i) {
      const int rowb = m0 + wr + i * 16 + quad * 4;
#pragma unroll
      for (int r = 0; r < 4; ++r)
        C[(size_t)(rowb + r) * ldc + col] = acc[i][j][r] + bv;
    }
  }
}

// ---------------------------------------------------------------------------
extern "C" void kernel_launch(void* const* d_in, const int* in_sizes, int n_in,
                              void* d_out, int out_size, void* d_ws, size_t ws_size,
                              hipStream_t stream) {
  const float* x     = (const float*)d_in[0];
  const float* w_qkv = (const float*)d_in[1];
  const float* w_out = (const float*)d_in[2];
  const float* b_out = (const float*)d_in[3];
  float* out = (float*)d_out;

  char* wbuf = (char*)d_in[1];
  char* obuf = (char*)d_out;

  bf16*  xb   = (bf16*)obuf;                         // d_out[0,32)
  float* ctxp = (float*)(obuf + (size_t)33554432);   // d_out[32,48)
  bf16*  wkvb = (bf16*)(obuf + (size_t)50331648);    // d_out[48,50)
  bf16*  M2   = (bf16*)(obuf + (size_t)52428800);    // d_out[50,54)
  bf16*  wqT  = (bf16*)(obuf + (size_t)56623104);    // d_out[54,54.5)
  bf16*  W2   = (bf16*)wbuf;                         // wbuf[0,6): batches 0-2
  bf16*  W2b3 = (bf16*)d_in[2];                      // w_out buf: batch 3

  // 1) prep: xb convert + wkvb convert + wqT transpose
  fused_prep<<<8832, 256, 0, stream>>>(x, w_qkv, xb, wkvb, wqT);

  // 2) fused kv-GEMM + softmax + ctx partials (all-bf16 async + XCD swizzle)
  kv_softmax_ctx<<<1024, 256, 0, stream>>>(xb, wkvb, ctxp);

  // 3) M2 = w_out folded through summed ctx -> d_out[50,54)
  build_m2<<<dim3(8, 32), 256, 0, stream>>>(w_out, ctxp, M2);

  // 4) W2 = M2 @ wqT^T; rows<3072 -> wbuf[0,6), rows>=3072 -> w_out buf.
  gemm_bt<bf16><<<256, 256, 0, stream>>>(
      M2, 512, wqT, 32, W2, 1024, 512, W2b3, 3072);

  // 5) out = bf16(x) @ W2[b]^T + b_out -> d_out (xb dead; reads pristine x).
  gemm_f32a<<<1024, 256, 0, stream>>>(
      x, W2, (size_t)1048576, W2b3, b_out, out, DIM);
}

// Round 17
// 256.603 us; speedup vs baseline: 1.0299x; 1.0299x over previous
//
#include <hip/hip_runtime.h>
#include <hip/hip_bf16.h>

using bf16 = __hip_bfloat16;
typedef __attribute__((ext_vector_type(8))) short short8;
typedef __attribute__((ext_vector_type(4))) float floatx4;

#define NB 4
#define NSEQ 4096
#define DIM 1024
#define INNER 512
#define TOK (NB * NSEQ)   // 16384

// -------------------------- memory plan (no d_ws) ---------------------------
// x buf (64 MiB fp32): PRISTINE (read by stages 2 and 6).
// d_out (64 MiB):
//   [0,32)   kv bf16 [16384][1024]   (stage 2 writes, stage 3 reads)
//   [32,34)  wkvb bf16 [1024][1024]  (stage 1; dead after stage 2)
//   [34,38)  M2 bf16 [4096][512]     (stage 4 writes; stage 5 reads)
//   [38,39)  wqT bf16 [1024][512]    (stage 1; dead after stage 5)
//   [40,48)  ctx_part fp32 [16][32][64][64] (stage 3 writes; stage 4 reads)
//   [0,64)   final output            (stage 6 — reads NOTHING in d_out)
// w_qkv buf (6 MiB fp32): stage 1 reads; then stage 5 overwrites with W2
//   batches 0..2 bf16.
// w_out buf (2 MiB fp32): stage 4 reads; then stage 5 overwrites W2 batch 3.
// R16 verdict: gemm_f32a (fp32-A reg-staged once + async-B, 4 blk/CU, XCD
// swizzle) is BW-bound at 54us / 2.55 TB/s — faster than the 61-62us 3-phase
// gemm256f it replaces here (stages 2 and 6). All other kernels are the
// R6/R7-verified set (best measured totals of the session).

__device__ inline unsigned short f2bf(float x) {
  union { bf16 h; unsigned short u; } c; c.h = __float2bfloat16(x); return c.u;
}
__device__ inline float bf2f(unsigned short u) {
  return __uint_as_float((unsigned)u << 16);
}
__device__ inline uint4 pack8(const float4 a, const float4 b) {
  union { uint4 u; unsigned short h[8]; } p;
  p.h[0] = f2bf(a.x); p.h[1] = f2bf(a.y); p.h[2] = f2bf(a.z); p.h[3] = f2bf(a.w);
  p.h[4] = f2bf(b.x); p.h[5] = f2bf(b.y); p.h[6] = f2bf(b.z); p.h[7] = f2bf(b.w);
  return p.u;
}

// async global->LDS, 16 B per lane; HW writes lane i at ldsbase + i*16.
__device__ inline void gload_lds16(const bf16* g, bf16* ldsbase) {
  __builtin_amdgcn_global_load_lds(
      (const __attribute__((address_space(1))) void*)g,
      (__attribute__((address_space(3))) void*)ldsbase, 16, 0, 0);
}

// ---------------------------------------------------------------------------
// stage 1: blocks [0,512)  convert w_kv fp32 -> wkvb bf16
//          blocks [512,640) transpose wq -> wqT bf16   (R6-verified)
// ---------------------------------------------------------------------------
__global__ __launch_bounds__(256)
void fused_prep(const float* __restrict__ w_qkv, bf16* __restrict__ wkvb,
                bf16* __restrict__ wqT) {
  const int tid = threadIdx.x;
  const int blk = blockIdx.x;

  if (blk < 512) {
    const size_t i = (size_t)blk * 256 + tid;
    const float* src = w_qkv + (size_t)INNER * DIM + i * 8;
    *(uint4*)(wkvb + i * 8) = pack8(((const float4*)src)[0], ((const float4*)src)[1]);
  } else {
    __shared__ unsigned short t[64 * 68];
    const int q  = blk - 512;
    const int c0 = (q & 15) * 64;
    const int r0 = (q >> 4) * 64;
#pragma unroll
    for (int l = 0; l < 4; ++l) {
      const int s = l * 256 + tid;
      const int row = s >> 4, col4 = s & 15;
      const float4 v = *(const float4*)(w_qkv + (size_t)(r0 + row) * 1024 + c0 + col4 * 4);
      t[row * 68 + col4 * 4 + 0] = f2bf(v.x);
      t[row * 68 + col4 * 4 + 1] = f2bf(v.y);
      t[row * 68 + col4 * 4 + 2] = f2bf(v.z);
      t[row * 68 + col4 * 4 + 3] = f2bf(v.w);
    }
    __syncthreads();
#pragma unroll
    for (int l = 0; l < 2; ++l) {
      const int s = l * 256 + tid;
      const int cc = s >> 3, g = s & 7;
      union { uint4 u; unsigned short h[8]; } o;
#pragma unroll
      for (int u = 0; u < 8; ++u) o.h[u] = t[(g * 8 + u) * 68 + cc];
      *(uint4*)((unsigned short*)wqT + (size_t)(c0 + cc) * 512 + r0 + g * 8) = o.u;
    }
  }
}

// ---------------------------------------------------------------------------
// gemm_f32a<TO,BIAS,BATCH>: C = bf16(A_fp32)[16384,1024] @ W[1024,1024]^T.
// R16-measured kernel (54us, 2.55 TB/s, BW-bound; 0 bank conflicts).
// 128x128 tiles, grid 1024, XCD swizzle: m_tile=(p&7)+(p>>6)*8 (bijective),
// n_tile=(p>>3)&7 — 8 n-blocks of an m-tile share the A-panel on one XCD.
// A: fp32 reg-load (single set) -> cvt -> conflict-free b128 ds_write at XOR
// slot (lcol^lrow) (R5-verified geometry). B: async gload_lds. 4 blk/CU.
// BATCH: W2 batches (batch = m_tile>>5; batch 3 lives in Walt).
// ---------------------------------------------------------------------------
template <typename TO, bool BIAS, bool BATCH>
__global__ __launch_bounds__(256, 4)
void gemm_f32a(const float* __restrict__ A,
               const bf16* __restrict__ W, size_t wbatch,
               const bf16* __restrict__ Walt,
               const float* __restrict__ bias,
               TO* __restrict__ C, int ldc) {
  __shared__ __align__(16) bf16 As[128 * 64];
  __shared__ __align__(16) bf16 Bs[128 * 64];

  const int tid    = threadIdx.x;
  const int p      = blockIdx.x;
  const int n_tile = (p >> 3) & 7;
  const int m_tile = (p & 7) + (p >> 6) * 8;   // 0..127, XCD-contiguous
  const int m0 = m_tile * 128, n0 = n_tile * 128;
  const bf16* Wp = W;
  if constexpr (BATCH) {
    const int batch = m_tile >> 5;
    Wp = (batch == 3) ? Walt : W + (size_t)batch * wbatch;
  }

  const int wave = tid >> 6;
  const int lane = tid & 63;
  const int wr   = (wave >> 1) * 64;
  const int wc   = (wave & 1) * 64;
  const int quad = lane >> 4;
  const int r16  = lane & 15;
  const int rxor = r16 & 7;
  const int lrow = lane >> 3;
  const int lcol = lane & 7;
  const int gchunk = lcol ^ lrow;
  const int wb = wave * 8 + lrow;

  const float* Ax = A + (size_t)(m0 + wb) * 1024 + lcol * 8;

  floatx4 acc[4][4];
#pragma unroll
  for (int i = 0; i < 4; ++i)
#pragma unroll
    for (int j = 0; j < 4; ++j) acc[i][j] = (floatx4)0.0f;

  for (int kt = 0; kt < 16; ++kt) {
    const int k0 = kt << 6;
#pragma unroll
    for (int t = 0; t < 4; ++t) {
      const int s   = wave * 4 + t;
      const int row = s * 8 + lrow;
      gload_lds16(Wp + (size_t)(n0 + row) * 1024 + k0 + gchunk * 8, Bs + s * 512);
    }
    float4 rA[8];
#pragma unroll
    for (int l = 0; l < 4; ++l) {
      rA[2 * l]     = *(const float4*)(Ax + (size_t)l * 32768 + k0);
      rA[2 * l + 1] = *(const float4*)(Ax + (size_t)l * 32768 + k0 + 4);
    }
#pragma unroll
    for (int l = 0; l < 4; ++l) {
      const int row = l * 32 + wb;       // row&7 == lrow
      *(uint4*)(As + row * 64 + ((lcol ^ lrow) << 3)) = pack8(rA[2 * l], rA[2 * l + 1]);
    }
    __syncthreads();   // drains vm (Bs landed) + lgkm (As writes visible)
#pragma unroll
    for (int kk = 0; kk < 64; kk += 32) {
      const int cbase = kk >> 3;
      short8 af[4], bfg[4];
#pragma unroll
      for (int i = 0; i < 4; ++i)
        af[i] = *(const short8*)(As + (wr + i * 16 + r16) * 64 + (((quad + cbase) ^ rxor) << 3));
#pragma unroll
      for (int j = 0; j < 4; ++j)
        bfg[j] = *(const short8*)(Bs + (wc + j * 16 + r16) * 64 + (((quad + cbase) ^ rxor) << 3));
#pragma unroll
      for (int i = 0; i < 4; ++i)
#pragma unroll
        for (int j = 0; j < 4; ++j)
          acc[i][j] = __builtin_amdgcn_mfma_f32_16x16x32_bf16(af[i], bfg[j], acc[i][j], 0, 0, 0);
    }
    __syncthreads();
  }

  // D mapping (verified m89/m91): row = quad*4 + reg, col = lane&15
#pragma unroll
  for (int j = 0; j < 4; ++j) {
    const int col = n0 + wc + j * 16 + r16;
    const float bv = BIAS ? bias[col] : 0.0f;
#pragma unroll
    for (int i = 0; i < 4; ++i) {
      const int rowb = m0 + wr + i * 16 + quad * 4;
#pragma unroll
      for (int r = 0; r < 4; ++r) {
        const float v = acc[i][j][r] + bv;
        if constexpr (sizeof(TO) == 2)
          C[(size_t)(rowb + r) * ldc + col] = __float2bfloat16(v);
        else
          C[(size_t)(rowb + r) * ldc + col] = v;
      }
    }
  }
}

// ---------------------------------------------------------------------------
// stage 3: softmax(k over dh=64) + ctx_part[slice][bh][d][e] (plain stores,
// no atomics — R7-verified). Grid 512 = 32 bh x 16 slices.
// ---------------------------------------------------------------------------
__global__ __launch_bounds__(256)
void softmax_context(const unsigned short* __restrict__ kv,
                     float* __restrict__ ctx_part) {
  __shared__ unsigned short skT[64 * 130];
  __shared__ unsigned short vT [64 * 130];

  const int tid   = threadIdx.x;
  const int wave  = tid >> 6;
  const int lane  = tid & 63;
  const int bh    = blockIdx.x >> 4;
  const int slice = blockIdx.x & 15;
  const int b     = bh >> 3, h = bh & 7;

  const int quad = lane >> 4;
  const int r16  = lane & 15;
  const int d0   = wave * 16;

  floatx4 acc[4];
#pragma unroll
  for (int j = 0; j < 4; ++j) acc[j] = (floatx4)0.0f;

  const int rgrp = tid >> 3;
  const int c    = tid & 7;

  for (int ch = 0; ch < 2; ++ch) {
#pragma unroll
    for (int p = 0; p < 4; ++p) {
      const int r = p * 32 + rgrp;
      const size_t rowbase =
          (size_t)(b * NSEQ + slice * 256 + ch * 128 + r) * 1024 + h * 64;
      const uint4 k8 = *(const uint4*)(kv + rowbase + c * 8);
      const uint4 v8 = *(const uint4*)(kv + rowbase + 512 + c * 8);
      const unsigned short* kb = (const unsigned short*)&k8;
      const unsigned short* vb = (const unsigned short*)&v8;

      float kf[8];
#pragma unroll
      for (int j = 0; j < 8; ++j) kf[j] = bf2f(kb[j]);
      float mx = kf[0];
#pragma unroll
      for (int j = 1; j < 8; ++j) mx = fmaxf(mx, kf[j]);
      mx = fmaxf(mx, __shfl_xor(mx, 1, 64));
      mx = fmaxf(mx, __shfl_xor(mx, 2, 64));
      mx = fmaxf(mx, __shfl_xor(mx, 4, 64));
      float e[8]; float s = 0.0f;
#pragma unroll
      for (int j = 0; j < 8; ++j) { e[j] = __expf(kf[j] - mx); s += e[j]; }
      s += __shfl_xor(s, 1, 64);
      s += __shfl_xor(s, 2, 64);
      s += __shfl_xor(s, 4, 64);
      const float inv = 1.0f / s;
#pragma unroll
      for (int j = 0; j < 8; ++j) {
        const int d = c * 8 + j;
        skT[d * 130 + r] = f2bf(e[j] * inv);
        vT [d * 130 + r] = vb[j];
      }
    }
    __syncthreads();

#pragma unroll
    for (int kk = 0; kk < 4; ++kk) {
      const int kof = kk * 32 + quad * 8;
      union { short8 v; unsigned u[4]; } afr;
      {
        const unsigned* q = (const unsigned*)(skT + (d0 + r16) * 130 + kof);
        afr.u[0] = q[0]; afr.u[1] = q[1]; afr.u[2] = q[2]; afr.u[3] = q[3];
      }
#pragma unroll
      for (int j = 0; j < 4; ++j) {
        union { short8 v; unsigned u[4]; } bfr;
        const unsigned* q = (const unsigned*)(vT + (j * 16 + r16) * 130 + kof);
        bfr.u[0] = q[0]; bfr.u[1] = q[1]; bfr.u[2] = q[2]; bfr.u[3] = q[3];
        acc[j] = __builtin_amdgcn_mfma_f32_16x16x32_bf16(afr.v, bfr.v, acc[j], 0, 0, 0);
      }
    }
    __syncthreads();
  }

  float* cg = ctx_part + ((size_t)slice * 32 + bh) * 4096;
#pragma unroll
  for (int j = 0; j < 4; ++j) {
    const int e = j * 16 + r16;
#pragma unroll
    for (int r = 0; r < 4; ++r) {
      const int d = d0 + quad * 4 + r;
      cg[d * 64 + e] = acc[j][r];
    }
  }
}

// ---------------------------------------------------------------------------
// stage 4: M2 = w_out folded through ctx (16-slice partial sum) — R7-verified.
// ---------------------------------------------------------------------------
__global__ __launch_bounds__(256)
void build_m2(const float* __restrict__ w_out, const float* __restrict__ ctx_part,
              bf16* __restrict__ M2) {
  __shared__ unsigned short wo_s[128 * 68];
  __shared__ __align__(16) float ctx_s[4096];

  const int tid = threadIdx.x;
  const int bh  = blockIdx.y;
  const int b   = bh >> 3, h = bh & 7;
  const int o0  = blockIdx.x * 128;

#pragma unroll
  for (int l = 0; l < 8; ++l) {
    const int s = l * 256 + tid;
    const int row = s >> 4, col4 = s & 15;
    const float4 v = *(const float4*)(w_out + (size_t)(o0 + row) * 512 + h * 64 + col4 * 4);
    wo_s[row * 68 + col4 * 4 + 0] = f2bf(v.x);
    wo_s[row * 68 + col4 * 4 + 1] = f2bf(v.y);
    wo_s[row * 68 + col4 * 4 + 2] = f2bf(v.z);
    wo_s[row * 68 + col4 * 4 + 3] = f2bf(v.w);
  }
  // ctx_s = sum over 16 slice partials (slice stride = 32*4096 fp32)
  const float4* cg = (const float4*)(ctx_part + (size_t)bh * 4096);
#pragma unroll
  for (int l = 0; l < 4; ++l) {
    const int idx = l * 256 + tid;
    float4 s = make_float4(0.f, 0.f, 0.f, 0.f);
#pragma unroll
    for (int sl = 0; sl < 16; ++sl) {
      const float4 v = cg[(size_t)sl * 32768 + idx];
      s.x += v.x; s.y += v.y; s.z += v.z; s.w += v.w;
    }
    ((float4*)ctx_s)[idx] = s;
  }
  __syncthreads();

  const int o_loc = tid & 127;
  const int dbase = (tid >> 7) * 32;
  float acc[32];
#pragma unroll
  for (int d = 0; d < 32; ++d) acc[d] = 0.0f;

  for (int e = 0; e < 64; ++e) {
    const float wf = bf2f(wo_s[o_loc * 68 + e]);
#pragma unroll
    for (int d = 0; d < 32; ++d)
      acc[d] += wf * ctx_s[(dbase + d) * 64 + e];
  }

  union { uint4 u[4]; unsigned short hh[32]; } o;
#pragma unroll
  for (int d = 0; d < 32; ++d) o.hh[d] = f2bf(acc[d]);
  unsigned short* dst = (unsigned short*)M2 + (size_t)(b * 1024 + o0 + o_loc) * 512 + h * 64 + dbase;
#pragma unroll
  for (int i = 0; i < 4; ++i) ((uint4*)dst)[i] = o.u[i];
}

// ---------------------------------------------------------------------------
// stage 5: 128x128 bf16 GEMM (W2 = M2 @ wqT^T). Rows >= msplit go to Calt.
// ---------------------------------------------------------------------------
template <typename TO>
__global__ __launch_bounds__(256, 4)
void gemm_bt(const bf16* __restrict__ A, int lda,
             const bf16* __restrict__ W, int mTiles,
             TO* __restrict__ C, int ldc, int K,
             TO* __restrict__ Calt, int msplit) {
  __shared__ __align__(16) bf16 As[128 * 64];
  __shared__ __align__(16) bf16 Bs[128 * 64];

  const int tid    = threadIdx.x;
  const int p      = blockIdx.x;
  const int m_tile = p % mTiles;
  const int n_tile = p / mTiles;
  const int m0     = m_tile * 128;
  const int n0     = n_tile * 128;

  const int wave = tid >> 6;
  const int lane = tid & 63;
  const int wr   = (wave >> 1) * 64;
  const int wc   = (wave & 1) * 64;
  const int quad = lane >> 4;
  const int r16  = lane & 15;
  const int rxor = r16 & 7;
  const int lrow = lane >> 3;
  const int lcol = lane & 7;
  const int gchunk = lcol ^ lrow;

  floatx4 acc[4][4];
#pragma unroll
  for (int i = 0; i < 4; ++i)
#pragma unroll
    for (int j = 0; j < 4; ++j) acc[i][j] = (floatx4)0.0f;

  const int ksteps = K >> 6;
  for (int kt = 0; kt < ksteps; ++kt) {
    const int k0 = kt << 6;
#pragma unroll
    for (int t = 0; t < 4; ++t) {
      const int s   = wave * 4 + t;
      const int row = s * 8 + lrow;
      gload_lds16(A + (size_t)(m0 + row) * lda + k0 + gchunk * 8, As + s * 512);
      gload_lds16(W + (size_t)(n0 + row) * K   + k0 + gchunk * 8, Bs + s * 512);
    }
    __syncthreads();
#pragma unroll
    for (int kk = 0; kk < 64; kk += 32) {
      const int cbase = kk >> 3;
      short8 af[4], bfg[4];
#pragma unroll
      for (int i = 0; i < 4; ++i)
        af[i] = *(const short8*)(As + (wr + i * 16 + r16) * 64 + (((quad + cbase) ^ rxor) << 3));
#pragma unroll
      for (int j = 0; j < 4; ++j)
        bfg[j] = *(const short8*)(Bs + (wc + j * 16 + r16) * 64 + (((quad + cbase) ^ rxor) << 3));
#pragma unroll
      for (int i = 0; i < 4; ++i)
#pragma unroll
        for (int j = 0; j < 4; ++j)
          acc[i][j] = __builtin_amdgcn_mfma_f32_16x16x32_bf16(af[i], bfg[j], acc[i][j], 0, 0, 0);
    }
    __syncthreads();
  }

  TO* Cb = C; int radj = 0;
  if (Calt && m0 >= msplit) { Cb = Calt; radj = msplit; }
#pragma unroll
  for (int j = 0; j < 4; ++j) {
    const int col = n0 + wc + j * 16 + r16;
#pragma unroll
    for (int i = 0; i < 4; ++i) {
      const int rowb = m0 + wr + i * 16 + quad * 4 - radj;
#pragma unroll
      for (int r = 0; r < 4; ++r)
        Cb[(size_t)(rowb + r) * ldc + col] = __float2bfloat16(acc[i][j][r]);
    }
  }
}

// ---------------------------------------------------------------------------
extern "C" void kernel_launch(void* const* d_in, const int* in_sizes, int n_in,
                              void* d_out, int out_size, void* d_ws, size_t ws_size,
                              hipStream_t stream) {
  const float* x     = (const float*)d_in[0];
  const float* w_qkv = (const float*)d_in[1];
  const float* w_out = (const float*)d_in[2];
  const float* b_out = (const float*)d_in[3];
  float* out = (float*)d_out;

  char* wbuf = (char*)d_in[1];
  char* obuf = (char*)d_out;

  bf16*  kv   = (bf16*)obuf;                         // d_out[0,32)
  bf16*  wkvb = (bf16*)(obuf + (size_t)33554432);    // d_out[32,34)
  bf16*  M2   = (bf16*)(obuf + (size_t)35651584);    // d_out[34,38)
  bf16*  wqT  = (bf16*)(obuf + (size_t)39845888);    // d_out[38,39)
  float* ctxp = (float*)(obuf + (size_t)41943040);   // d_out[40,48)
  bf16*  W2   = (bf16*)wbuf;                         // wbuf[0,6): batches 0-2
  bf16*  W2b3 = (bf16*)d_in[2];                      // w_out buf: batch 3

  // 1) prep: wkvb convert + wqT transpose
  fused_prep<<<640, 256, 0, stream>>>(w_qkv, wkvb, wqT);

  // 2) kv = bf16(x) @ wkvb^T -> d_out[0,32). R16-measured gemm_f32a shape.
  gemm_f32a<bf16, false, false><<<1024, 256, 0, stream>>>(
      x, wkvb, 0, nullptr, nullptr, kv, 1024);

  // 3) ctx partials = softmax(k)^T v (plain stores, 16 partials per bh)
  softmax_context<<<512, 256, 0, stream>>>((const unsigned short*)kv, ctxp);

  // 4) M2 = w_out folded through summed ctx -> d_out[34,38)
  build_m2<<<dim3(8, 32), 256, 0, stream>>>(w_out, ctxp, M2);

  // 5) W2 = M2 @ wqT^T; rows<3072 -> wbuf[0,6), rows>=3072 -> w_out buf.
  gemm_bt<bf16><<<256, 256, 0, stream>>>(
      M2, 512, wqT, 32, W2, 1024, 512, W2b3, 3072);

  // 6) out = bf16(x) @ W2[b]^T + b_out -> d_out (reads nothing in d_out).
  gemm_f32a<float, true, true><<<1024, 256, 0, stream>>>(
      x, W2, (size_t)1048576, W2b3, b_out, out, DIM);
}